// Round 1
// baseline (743.593 us; speedup 1.0000x reference)
//
#include <hip/hip_runtime.h>
#include <hip/hip_bf16.h>

// Sizes (fixed by the problem)
#define B_  8
#define LQ  160
#define LK  160
#define D_  512
#define H_  512
#define C_  8
#define S_  64
#define R_  8

// ---------------------------------------------------------------------------
// Generic fp32 GEMM: C[m,n] = sum_k A[m,k] * W[n,k] + bias[n]
// A row-major [M,K] (lda), W row-major [N,K], 64x64 tile, 256 threads, 4x4 micro.
// MODE 0: plain store C[m*ldc+n]
// MODE 1: y1 permuted store: C[m*4096 + z*512 + (n%64)*8 + (n/64)]
// MODE 2: y0 transposed store: C[b*655360 + (z*512 + (n%64)*8 + n/64)*160 + (m%160)]
// ---------------------------------------------------------------------------
template <int MODE>
__global__ __launch_bounds__(256) void gemm64(
    const float* __restrict__ A, int lda, int aB,
    const float* __restrict__ W, int wB,
    const float* __restrict__ Bi, int bB,
    float* __restrict__ C, int ldc, int K)
{
    const int z  = blockIdx.z;
    const int m0 = blockIdx.y << 6;
    const int n0 = blockIdx.x << 6;
    A  += (long)z * aB;
    W  += (long)z * wB;
    Bi += (long)z * bB;

    const int tid = threadIdx.x;
    const int tm  = tid >> 4;          // 0..15
    const int tn  = tid & 15;          // 0..15
    const int lr  = tid >> 2;          // 0..63 (load row)
    const int lk4 = (tid & 3) << 2;    // 0,4,8,12 (load k group)

    __shared__ float As[16][64];
    __shared__ float Ws[16][64];

    float acc[4][4];
#pragma unroll
    for (int i = 0; i < 4; i++)
#pragma unroll
        for (int j = 0; j < 4; j++) acc[i][j] = 0.f;

    for (int k0 = 0; k0 < K; k0 += 16) {
        const float4 av = *(const float4*)(A + (long)(m0 + lr) * lda + k0 + lk4);
        const float4 wv = *(const float4*)(W + (long)(n0 + lr) * K   + k0 + lk4);
        __syncthreads();
        As[lk4 + 0][lr] = av.x; As[lk4 + 1][lr] = av.y;
        As[lk4 + 2][lr] = av.z; As[lk4 + 3][lr] = av.w;
        Ws[lk4 + 0][lr] = wv.x; Ws[lk4 + 1][lr] = wv.y;
        Ws[lk4 + 2][lr] = wv.z; Ws[lk4 + 3][lr] = wv.w;
        __syncthreads();
#pragma unroll
        for (int kk = 0; kk < 16; kk++) {
            const float4 a4 = *(const float4*)(&As[kk][tm << 2]);
            const float4 b4 = *(const float4*)(&Ws[kk][tn << 2]);
            const float aa[4] = {a4.x, a4.y, a4.z, a4.w};
            const float bb[4] = {b4.x, b4.y, b4.z, b4.w};
#pragma unroll
            for (int i = 0; i < 4; i++)
#pragma unroll
                for (int j = 0; j < 4; j++)
                    acc[i][j] = fmaf(aa[i], bb[j], acc[i][j]);
        }
    }

    const float4 bv = *(const float4*)(Bi + n0 + (tn << 2));
    const float bArr[4] = {bv.x, bv.y, bv.z, bv.w};

    if constexpr (MODE == 0) {
#pragma unroll
        for (int i = 0; i < 4; i++) {
            float4 v;
            v.x = acc[i][0] + bArr[0]; v.y = acc[i][1] + bArr[1];
            v.z = acc[i][2] + bArr[2]; v.w = acc[i][3] + bArr[3];
            *(float4*)(C + (long)(m0 + (tm << 2) + i) * ldc + n0 + (tn << 2)) = v;
        }
    } else if constexpr (MODE == 1) {
#pragma unroll
        for (int j = 0; j < 4; j++) {
            const int n = n0 + (tn << 2) + j;
            const int s = n & 63, r = n >> 6;
            const long col = (long)z * 512 + (s << 3) + r;
#pragma unroll
            for (int i = 0; i < 4; i++)
                C[(long)(m0 + (tm << 2) + i) * 4096 + col] = acc[i][j] + bArr[j];
        }
    } else {
        const int m    = m0 + (tm << 2);
        const int bidx = m / 160;
        const int kk_  = m - bidx * 160;
#pragma unroll
        for (int j = 0; j < 4; j++) {
            const int n = n0 + (tn << 2) + j;
            const int s = n & 63, r = n >> 6;
            float4 v;
            v.x = acc[0][j] + bArr[j]; v.y = acc[1][j] + bArr[j];
            v.z = acc[2][j] + bArr[j]; v.w = acc[3][j] + bArr[j];
            *(float4*)(C + (long)bidx * 655360 + ((long)z * 512 + (s << 3) + r) * 160 + kk_) = v;
        }
    }
}

// ---------------------------------------------------------------------------
// Heavy fused kernel: per (b, q-tile of 4): scores over all k, softmax, att@vv.
// y1p: [B][LQ][C][S][R]   (per-(c) slab staged to LDS, broadcast reads)
// y0t: [B][C][S][R][LK]   (lane-coalesced over k)
// Lane-local trick: after signed sqrt, sum_s v^2 = sum_s |z|, so chunk norm
// needs only running |z| sum; normalize factors out of the w_bo dot.
// ---------------------------------------------------------------------------
__global__ __launch_bounds__(192) void score_att(
    const float* __restrict__ y1p, const float* __restrict__ y0t,
    const float* __restrict__ vv, const float* __restrict__ wbo,
    const float* __restrict__ bbo, float* __restrict__ attedT)
{
    const int b   = blockIdx.y;
    const int q0  = blockIdx.x << 2;
    const int tid = threadIdx.x;
    const int k   = tid;

    __shared__ float y1c[4][512];   // [q][s*8+r] for current chunk c
    __shared__ float scs[4][160];
    __shared__ float invd[4];

    const float bb = bbo[0];
    float sc[4] = {bb, bb, bb, bb};
    const float* y0b = y0t + (long)b * 655360 + k;
    const long y1base = (long)(b * LQ + q0) * 4096;

    for (int c = 0; c < 8; c++) {
        __syncthreads();
        for (int i = tid; i < 512; i += 192) {  // 512 float4s = 4q x 512 floats
            const int qq = i >> 7, e = i & 127;
            ((float4*)&y1c[0][0])[i] =
                *(const float4*)(y1p + y1base + (long)qq * 4096 + c * 512 + (e << 2));
        }
        __syncthreads();
        if (k < LK) {
            float num[4] = {0.f, 0.f, 0.f, 0.f};
            float den[4] = {0.f, 0.f, 0.f, 0.f};
            const float* wb  = wbo + (c << 6);
            const float* ybc = y0b + (long)(c << 6) * 1280;
            for (int s = 0; s < 64; s++) {
                const float* yp = ybc + s * 1280;
                float a[8];
#pragma unroll
                for (int r = 0; r < 8; r++) a[r] = yp[r * 160];
                const float w = wb[s];
#pragma unroll
                for (int q = 0; q < 4; q++) {
                    const float* yq = &y1c[q][s << 3];
                    float zq = 0.f;
#pragma unroll
                    for (int r = 0; r < 8; r++) zq = fmaf(a[r], yq[r], zq);
                    const float az = fabsf(zq);
                    num[q] = fmaf(copysignf(sqrtf(az), zq), w, num[q]);
                    den[q] += az;
                }
            }
#pragma unroll
            for (int q = 0; q < 4; q++)
                sc[q] += num[q] / fmaxf(sqrtf(den[q]), 1e-12f);
        }
    }
    if (k < LK) {
#pragma unroll
        for (int q = 0; q < 4; q++) scs[q][k] = sc[q];
    }
    __syncthreads();

    if (tid < 64) {
#pragma unroll
        for (int q = 0; q < 4; q++) {
            float m = -1e30f;
            for (int j = tid; j < LK; j += 64) m = fmaxf(m, scs[q][j]);
#pragma unroll
            for (int off = 32; off; off >>= 1) m = fmaxf(m, __shfl_xor(m, off, 64));
            float sum = 0.f;
            for (int j = tid; j < LK; j += 64) {
                const float e = expf(scs[q][j] - m);
                scs[q][j] = e;
                sum += e;
            }
#pragma unroll
            for (int off = 32; off; off >>= 1) sum += __shfl_xor(sum, off, 64);
            if (tid == 0) invd[q] = 1.f / sum;
        }
    }
    __syncthreads();

    float acc[3][4];
#pragma unroll
    for (int j2 = 0; j2 < 3; j2++)
#pragma unroll
        for (int q = 0; q < 4; q++) acc[j2][q] = 0.f;

    const float* vb = vv + (long)b * (LK * 512);
    for (int kk2 = 0; kk2 < LK; kk2++) {
        float w4[4];
#pragma unroll
        for (int q = 0; q < 4; q++) w4[q] = scs[q][kk2];
        const float* vr = vb + kk2 * 512;
#pragma unroll
        for (int j2 = 0; j2 < 3; j2++) {
            const int h = tid + j2 * 192;
            if (h < 512) {
                const float vx = vr[h];
#pragma unroll
                for (int q = 0; q < 4; q++) acc[j2][q] = fmaf(w4[q], vx, acc[j2][q]);
            }
        }
    }
#pragma unroll
    for (int j2 = 0; j2 < 3; j2++) {
        const int h = tid + j2 * 192;
        if (h < 512) {
#pragma unroll
            for (int q = 0; q < 4; q++)
                attedT[((long)b * 512 + h) * 160 + q0 + q] = acc[j2][q] * invd[q];
        }
    }
}

// ---------------------------------------------------------------------------
extern "C" void kernel_launch(void* const* d_in, const int* in_sizes, int n_in,
                              void* d_out, int out_size, void* d_ws, size_t ws_size,
                              hipStream_t stream) {
    const float* v    = (const float*)d_in[0];
    const float* kin  = (const float*)d_in[1];
    const float* q    = (const float*)d_in[2];
    const float* w_v  = (const float*)d_in[3];
    const float* b_v  = (const float*)d_in[4];
    const float* w_k  = (const float*)d_in[5];
    const float* b_k  = (const float*)d_in[6];
    const float* w_q  = (const float*)d_in[7];
    const float* b_q  = (const float*)d_in[8];
    const float* w0   = (const float*)d_in[9];
    const float* b0   = (const float*)d_in[10];
    const float* w1   = (const float*)d_in[11];
    const float* b1   = (const float*)d_in[12];
    const float* wm0  = (const float*)d_in[13];
    const float* bm0  = (const float*)d_in[14];
    const float* wm1  = (const float*)d_in[15];
    const float* bm1  = (const float*)d_in[16];
    const float* w_bo = (const float*)d_in[17];
    const float* b_bo = (const float*)d_in[18];
    const float* w_m  = (const float*)d_in[19];
    const float* b_m  = (const float*)d_in[20];

    float* ws     = (float*)d_ws;
    float* vv     = ws;                  // 655360
    float* kk     = ws + 655360;         // 655360
    float* qq     = ws + 1310720;        // 655360
    float* x0     = ws + 1966080;        // 655360
    float* x1     = ws + 2621440;        // 655360
    float* y1p    = ws + 3276800;        // 5242880  [B][LQ][c][s][r]
    float* y0t    = ws + 8519680;        // 5242880  [B][c][s][r][LK]
    float* attedT = ws + 13762560;       // 655360   [B][512][LQ]

    dim3 blk(256);
    dim3 g(8, 20, 1);
    hipLaunchKernelGGL((gemm64<0>), g, blk, 0, stream, v,   512, 0, w_v, 0, b_v, 0, vv, 512, 512);
    hipLaunchKernelGGL((gemm64<0>), g, blk, 0, stream, kin, 512, 0, w_k, 0, b_k, 0, kk, 512, 512);
    hipLaunchKernelGGL((gemm64<0>), g, blk, 0, stream, q,   512, 0, w_q, 0, b_q, 0, qq, 512, 512);
    hipLaunchKernelGGL((gemm64<0>), g, blk, 0, stream, kk,  512, 0, w0,  0, b0,  0, x0, 512, 512);
    hipLaunchKernelGGL((gemm64<0>), g, blk, 0, stream, qq,  512, 0, w1,  0, b1,  0, x1, 512, 512);

    dim3 gy(8, 20, 8);
    hipLaunchKernelGGL((gemm64<2>), gy, blk, 0, stream, x0, 512, 64, wm0, 32768, bm0, 512, y0t, 0, 64);
    hipLaunchKernelGGL((gemm64<1>), gy, blk, 0, stream, x1, 512, 64, wm1, 32768, bm1, 512, y1p, 0, 64);

    hipLaunchKernelGGL(score_att, dim3(40, 8), dim3(192), 0, stream,
                       y1p, y0t, vv, w_bo, b_bo, attedT);

    hipLaunchKernelGGL((gemm64<0>), g, blk, 0, stream,
                       attedT, 512, 0, w_m, 0, b_m, 0, (float*)d_out, 512, 512);
}

// Round 3
// 475.996 us; speedup vs baseline: 1.5622x; 1.5622x over previous
//
#include <hip/hip_runtime.h>
#include <hip/hip_bf16.h>

#define B_  8
#define LQ  160
#define LK  160

// ---------------------------------------------------------------------------
// Multi-op fp32 GEMM with split-K.
// C[m,n] = sum_k A[m,k]*W[n,k] + bias[n], A [1280,512] lda=512, W [512,K], C ld 512.
// blockIdx.z = op*KSPLIT + kz. KSPLIT>1 => atomicAdd into pre-zeroed C
// (bias added by kz==0 partial).
// ---------------------------------------------------------------------------
struct GOps {
    const float* A[3];
    const float* W[3];
    const float* Bi[3];
    float*       C[3];
};

template <int KSPLIT>
__global__ __launch_bounds__(256) void gemm_ks(GOps ops, int K)
{
    const int op = blockIdx.z / KSPLIT;
    const int kz = blockIdx.z - op * KSPLIT;
    const float* __restrict__ A  = ops.A[op];
    const float* __restrict__ W  = ops.W[op];
    const float* __restrict__ Bi = ops.Bi[op];
    float* __restrict__       C  = ops.C[op];

    const int m0 = blockIdx.y << 6;
    const int n0 = blockIdx.x << 6;
    const int tid = threadIdx.x;
    const int tm  = tid >> 4;
    const int tn  = tid & 15;
    const int lr  = tid >> 2;
    const int lk4 = (tid & 3) << 2;

    __shared__ float As[16][64];
    __shared__ float Ws[16][64];

    float acc[4][4];
#pragma unroll
    for (int i = 0; i < 4; i++)
#pragma unroll
        for (int j = 0; j < 4; j++) acc[i][j] = 0.f;

    const int Klen = K / KSPLIT;
    const int kbeg = kz * Klen;
    const int kend = kbeg + Klen;

    for (int k0 = kbeg; k0 < kend; k0 += 16) {
        const float4 av = *(const float4*)(A + (long)(m0 + lr) * 512 + k0 + lk4);
        const float4 wv = *(const float4*)(W + (long)(n0 + lr) * K   + k0 + lk4);
        __syncthreads();
        As[lk4 + 0][lr] = av.x; As[lk4 + 1][lr] = av.y;
        As[lk4 + 2][lr] = av.z; As[lk4 + 3][lr] = av.w;
        Ws[lk4 + 0][lr] = wv.x; Ws[lk4 + 1][lr] = wv.y;
        Ws[lk4 + 2][lr] = wv.z; Ws[lk4 + 3][lr] = wv.w;
        __syncthreads();
#pragma unroll
        for (int kk = 0; kk < 16; kk++) {
            const float4 a4 = *(const float4*)(&As[kk][tm << 2]);
            const float4 b4 = *(const float4*)(&Ws[kk][tn << 2]);
            const float aa[4] = {a4.x, a4.y, a4.z, a4.w};
            const float bb[4] = {b4.x, b4.y, b4.z, b4.w};
#pragma unroll
            for (int i = 0; i < 4; i++)
#pragma unroll
                for (int j = 0; j < 4; j++)
                    acc[i][j] = fmaf(aa[i], bb[j], acc[i][j]);
        }
    }

    const float4 bv = *(const float4*)(Bi + n0 + (tn << 2));
    const float bArr[4] = {bv.x, bv.y, bv.z, bv.w};

    if constexpr (KSPLIT == 1) {
#pragma unroll
        for (int i = 0; i < 4; i++) {
            float4 v;
            v.x = acc[i][0] + bArr[0]; v.y = acc[i][1] + bArr[1];
            v.z = acc[i][2] + bArr[2]; v.w = acc[i][3] + bArr[3];
            *(float4*)(C + (long)(m0 + (tm << 2) + i) * 512 + n0 + (tn << 2)) = v;
        }
    } else {
#pragma unroll
        for (int i = 0; i < 4; i++) {
            float* crow = C + (long)(m0 + (tm << 2) + i) * 512 + n0 + (tn << 2);
#pragma unroll
            for (int j = 0; j < 4; j++) {
                float val = acc[i][j] + (kz == 0 ? bArr[j] : 0.f);
                atomicAdd(crow + j, val);
            }
        }
    }
}

// ---------------------------------------------------------------------------
// Fused per-chunk merge projections (K=64 GEMMs), both y0 and y1 in one launch.
// z in [0,16): z<8 -> y0 chunk z (transposed store), z>=8 -> y1 chunk z-8
// (permuted store).
// y0t: [B][c][s][r][LK]   y1p: [B][LQ][c][s][r]
// ---------------------------------------------------------------------------
__global__ __launch_bounds__(256) void y_proj(
    const float* __restrict__ x0, const float* __restrict__ wm0, const float* __restrict__ bm0,
    const float* __restrict__ x1, const float* __restrict__ wm1, const float* __restrict__ bm1,
    float* __restrict__ y0t, float* __restrict__ y1p)
{
    const int z   = blockIdx.z;
    const bool is1 = z >= 8;
    const int c   = is1 ? z - 8 : z;
    const float* A  = (is1 ? x1 : x0) + (c << 6);      // column slice, lda=512
    const float* W  = (is1 ? wm1 : wm0) + c * 32768;   // [512][64]
    const float* Bi = (is1 ? bm1 : bm0) + (c << 9);

    const int m0 = blockIdx.y << 6;
    const int n0 = blockIdx.x << 6;
    const int tid = threadIdx.x;
    const int tm  = tid >> 4;
    const int tn  = tid & 15;
    const int lr  = tid >> 2;
    const int lk4 = (tid & 3) << 2;

    __shared__ float As[16][64];
    __shared__ float Ws[16][64];

    float acc[4][4];
#pragma unroll
    for (int i = 0; i < 4; i++)
#pragma unroll
        for (int j = 0; j < 4; j++) acc[i][j] = 0.f;

    for (int k0 = 0; k0 < 64; k0 += 16) {
        const float4 av = *(const float4*)(A + (long)(m0 + lr) * 512 + k0 + lk4);
        const float4 wv = *(const float4*)(W + (long)(n0 + lr) * 64  + k0 + lk4);
        __syncthreads();
        As[lk4 + 0][lr] = av.x; As[lk4 + 1][lr] = av.y;
        As[lk4 + 2][lr] = av.z; As[lk4 + 3][lr] = av.w;
        Ws[lk4 + 0][lr] = wv.x; Ws[lk4 + 1][lr] = wv.y;
        Ws[lk4 + 2][lr] = wv.z; Ws[lk4 + 3][lr] = wv.w;
        __syncthreads();
#pragma unroll
        for (int kk = 0; kk < 16; kk++) {
            const float4 a4 = *(const float4*)(&As[kk][tm << 2]);
            const float4 b4 = *(const float4*)(&Ws[kk][tn << 2]);
            const float aa[4] = {a4.x, a4.y, a4.z, a4.w};
            const float bb[4] = {b4.x, b4.y, b4.z, b4.w};
#pragma unroll
            for (int i = 0; i < 4; i++)
#pragma unroll
                for (int j = 0; j < 4; j++)
                    acc[i][j] = fmaf(aa[i], bb[j], acc[i][j]);
        }
    }

    const float4 bv = *(const float4*)(Bi + n0 + (tn << 2));
    const float bArr[4] = {bv.x, bv.y, bv.z, bv.w};

    if (!is1) {
        const int m    = m0 + (tm << 2);
        const int bidx = m / 160;
        const int kk_  = m - bidx * 160;
#pragma unroll
        for (int j = 0; j < 4; j++) {
            const int n = n0 + (tn << 2) + j;
            const int s = n & 63, r = n >> 6;
            float4 v;
            v.x = acc[0][j] + bArr[j]; v.y = acc[1][j] + bArr[j];
            v.z = acc[2][j] + bArr[j]; v.w = acc[3][j] + bArr[j];
            *(float4*)(y0t + (long)bidx * 655360 + ((long)(c << 9) + (s << 3) + r) * 160 + kk_) = v;
        }
    } else {
#pragma unroll
        for (int j = 0; j < 4; j++) {
            const int n = n0 + (tn << 2) + j;
            const int s = n & 63, r = n >> 6;
            const long col = (long)(c << 9) + (s << 3) + r;
#pragma unroll
            for (int i = 0; i < 4; i++)
                y1p[(long)(m0 + (tm << 2) + i) * 4096 + col] = acc[i][j] + bArr[j];
        }
    }
}

// ---------------------------------------------------------------------------
// Per-(b, q-tile, c) partial scores: num/sqrt(den) for one chunk.
// XCD-aware decode: c = id%8 -> all 40 q-tiles of one (b,c) share an XCD's L2
// slab of y0t (327 KB).
// scores_p: [B][LQ][C][LK]
// ---------------------------------------------------------------------------
__global__ __launch_bounds__(192) void score_partial(
    const float* __restrict__ y1p, const float* __restrict__ y0t,
    const float* __restrict__ wbo, float* __restrict__ scores_p)
{
    const int id = blockIdx.x;
    const int c  = id & 7;
    const int j  = id >> 3;
    const int b  = j / 40;
    const int q0 = (j - b * 40) << 2;
    const int tid = threadIdx.x;
    const int k   = tid;

    __shared__ float y1c[4][512];   // [q][s*8+r] for chunk c

    const long y1base = (long)(b * LQ + q0) * 4096 + (c << 9);
    for (int t = tid; t < 512; t += 192) {
        const int qq = t >> 7, e = t & 127;
        ((float4*)&y1c[0][0])[t] =
            *(const float4*)(y1p + y1base + (long)qq * 4096 + (e << 2));
    }
    __syncthreads();
    if (k >= LK) return;

    const float* wb  = wbo + (c << 6);
    const float* ybc = y0t + (long)b * 655360 + (long)(c << 6) * 1280 + k;

    float num[4] = {0.f, 0.f, 0.f, 0.f};
    float den[4] = {0.f, 0.f, 0.f, 0.f};
    for (int s = 0; s < 64; s++) {
        const float* yp = ybc + s * 1280;
        float a[8];
#pragma unroll
        for (int r = 0; r < 8; r++) a[r] = yp[r * 160];
        const float w = wb[s];
#pragma unroll
        for (int q = 0; q < 4; q++) {
            const float* yq = &y1c[q][s << 3];
            float z = 0.f;
#pragma unroll
            for (int r = 0; r < 8; r++) z = fmaf(a[r], yq[r], z);
            const float az = fabsf(z);
            num[q] = fmaf(copysignf(sqrtf(az), z), w, num[q]);
            den[q] += az;
        }
    }
#pragma unroll
    for (int q = 0; q < 4; q++)
        scores_p[(((long)(b * LQ + q0 + q)) * 8 + c) * 160 + k] =
            num[q] / fmaxf(sqrtf(den[q]), 1e-12f);
}

// ---------------------------------------------------------------------------
// Sum partials over c, softmax over k, att@vv, write attedT [B][512][LQ]
// (= row-major input of the final linear after the torch transpose/view).
// b_bo dropped: softmax is shift-invariant.
// ---------------------------------------------------------------------------
__global__ __launch_bounds__(256) void softmax_attv(
    const float* __restrict__ scores_p, const float* __restrict__ vv,
    float* __restrict__ attedT)
{
    const int b  = blockIdx.y;
    const int q0 = blockIdx.x << 2;
    const int tid = threadIdx.x;

    __shared__ float scs[4][160];
    __shared__ float invd[4];

    for (int t = tid; t < 640; t += 256) {
        const int q = t / 160;
        const int k = t - q * 160;
        const float* sp = scores_p + ((long)(b * LQ + q0 + q)) * 1280 + k;
        float s = 0.f;
#pragma unroll
        for (int c = 0; c < 8; c++) s += sp[c * 160];
        scs[q][k] = s;
    }
    __syncthreads();

    const int w    = tid >> 6;
    const int lane = tid & 63;
    {
        const int q = w;
        float m = -1e30f;
        for (int kk = lane; kk < LK; kk += 64) m = fmaxf(m, scs[q][kk]);
#pragma unroll
        for (int off = 32; off; off >>= 1) m = fmaxf(m, __shfl_xor(m, off, 64));
        float sum = 0.f;
        for (int kk = lane; kk < LK; kk += 64) {
            const float e = __expf(scs[q][kk] - m);
            scs[q][kk] = e;
            sum += e;
        }
#pragma unroll
        for (int off = 32; off; off >>= 1) sum += __shfl_xor(sum, off, 64);
        if (lane == 0) invd[q] = 1.f / sum;
    }
    __syncthreads();

    float acc[2][4] = {{0.f,0.f,0.f,0.f},{0.f,0.f,0.f,0.f}};
    const float* vb = vv + (long)b * (LK * 512);
    for (int kk = 0; kk < LK; kk++) {
        const float* vr = vb + kk * 512;
        const float p0 = scs[0][kk], p1 = scs[1][kk];
        const float p2 = scs[2][kk], p3 = scs[3][kk];
        const float v0 = vr[tid], v1 = vr[tid + 256];
        acc[0][0] = fmaf(p0, v0, acc[0][0]); acc[0][1] = fmaf(p1, v0, acc[0][1]);
        acc[0][2] = fmaf(p2, v0, acc[0][2]); acc[0][3] = fmaf(p3, v0, acc[0][3]);
        acc[1][0] = fmaf(p0, v1, acc[1][0]); acc[1][1] = fmaf(p1, v1, acc[1][1]);
        acc[1][2] = fmaf(p2, v1, acc[1][2]); acc[1][3] = fmaf(p3, v1, acc[1][3]);
    }
#pragma unroll
    for (int j = 0; j < 2; j++) {
        const int h = tid + (j << 8);
#pragma unroll
        for (int q = 0; q < 4; q++)
            attedT[((long)b * 512 + h) * 160 + q0 + q] = acc[j][q] * invd[q];
    }
}

// ---------------------------------------------------------------------------
__global__ void fill2(float4* p1, int n1, float4* p2, int n2)
{
    const int i      = blockIdx.x * 256 + threadIdx.x;
    const int stride = gridDim.x * 256;
    const float4 z = {0.f, 0.f, 0.f, 0.f};
    for (int t = i; t < n1; t += stride) p1[t] = z;
    for (int t = i; t < n2; t += stride) p2[t] = z;
}

// ---------------------------------------------------------------------------
extern "C" void kernel_launch(void* const* d_in, const int* in_sizes, int n_in,
                              void* d_out, int out_size, void* d_ws, size_t ws_size,
                              hipStream_t stream) {
    const float* v    = (const float*)d_in[0];
    const float* kin  = (const float*)d_in[1];
    const float* q    = (const float*)d_in[2];
    const float* w_v  = (const float*)d_in[3];
    const float* b_v  = (const float*)d_in[4];
    const float* w_k  = (const float*)d_in[5];
    const float* b_k  = (const float*)d_in[6];
    const float* w_q  = (const float*)d_in[7];
    const float* b_q  = (const float*)d_in[8];
    const float* w0   = (const float*)d_in[9];
    const float* b0   = (const float*)d_in[10];
    const float* w1   = (const float*)d_in[11];
    const float* b1   = (const float*)d_in[12];
    const float* wm0  = (const float*)d_in[13];
    const float* bm0  = (const float*)d_in[14];
    const float* wm1  = (const float*)d_in[15];
    const float* bm1  = (const float*)d_in[16];
    const float* w_bo = (const float*)d_in[17];
    const float* b_m_bias_dummy = (const float*)d_in[18]; (void)b_m_bias_dummy; // b_bo unused
    const float* w_m  = (const float*)d_in[19];
    const float* b_m  = (const float*)d_in[20];

    float* ws       = (float*)d_ws;
    float* vv       = ws;                  // 655360
    float* kk       = ws + 655360;         // 655360
    float* qq       = ws + 1310720;        // 655360
    float* x0       = ws + 1966080;        // 655360
    float* x1       = ws + 2621440;        // 655360
    float* y1p      = ws + 3276800;        // 5242880  [B][LQ][c][s][r]
    float* y0t      = ws + 8519680;        // 5242880  [B][c][s][r][LK]
    float* attedT   = ws + 13762560;       // 655360   [B][512][LQ]
    float* scores_p = ws + 655360;         // 1638400, aliases kk/qq/x0 (dead by then)

    // zero atomic-accumulation targets: vv..x1 (5*655360) and d_out
    fill2<<<2048, 256, 0, stream>>>((float4*)ws, 819200, (float4*)d_out, 163840);

    GOps oA;
    oA.A[0] = v;   oA.W[0] = w_v; oA.Bi[0] = b_v; oA.C[0] = vv;
    oA.A[1] = kin; oA.W[1] = w_k; oA.Bi[1] = b_k; oA.C[1] = kk;
    oA.A[2] = q;   oA.W[2] = w_q; oA.Bi[2] = b_q; oA.C[2] = qq;
    hipLaunchKernelGGL((gemm_ks<2>), dim3(8, 20, 6), dim3(256), 0, stream, oA, 512);

    GOps oB;
    oB.A[0] = kk; oB.W[0] = w0; oB.Bi[0] = b0; oB.C[0] = x0;
    oB.A[1] = qq; oB.W[1] = w1; oB.Bi[1] = b1; oB.C[1] = x1;
    oB.A[2] = nullptr; oB.W[2] = nullptr; oB.Bi[2] = nullptr; oB.C[2] = nullptr;
    hipLaunchKernelGGL((gemm_ks<2>), dim3(8, 20, 4), dim3(256), 0, stream, oB, 512);

    hipLaunchKernelGGL(y_proj, dim3(8, 20, 16), dim3(256), 0, stream,
                       x0, wm0, bm0, x1, wm1, bm1, y0t, y1p);

    hipLaunchKernelGGL(score_partial, dim3(2560), dim3(192), 0, stream,
                       y1p, y0t, w_bo, scores_p);

    hipLaunchKernelGGL(softmax_attv, dim3(40, 8), dim3(256), 0, stream,
                       scores_p, vv, attedT);

    GOps oF;
    oF.A[0] = attedT; oF.W[0] = w_m; oF.Bi[0] = b_m; oF.C[0] = (float*)d_out;
    oF.A[1] = nullptr; oF.W[1] = nullptr; oF.Bi[1] = nullptr; oF.C[1] = nullptr;
    oF.A[2] = nullptr; oF.W[2] = nullptr; oF.Bi[2] = nullptr; oF.C[2] = nullptr;
    hipLaunchKernelGGL((gemm_ks<4>), dim3(8, 20, 4), dim3(256), 0, stream, oF, 512);
}

// Round 4
// 423.068 us; speedup vs baseline: 1.7576x; 1.1251x over previous
//
#include <hip/hip_runtime.h>
#include <hip/hip_bf16.h>

#define B_  8
#define LQ  160
#define LK  160

// ---------------------------------------------------------------------------
// Multi-op fp32 GEMM, full K, no atomics.
// C[m,n] = sum_k A[m,k]*W[n,k] + bias[n]; A [1280,512] lda=512, W [N=512,K=512],
// C ld 512. blockIdx.z selects op. 64x64 tile, 256 threads, 4x4 micro.
// ---------------------------------------------------------------------------
struct GOps {
    const float* A[3];
    const float* W[3];
    const float* Bi[3];
    float*       C[3];
};

__global__ __launch_bounds__(256) void gemm_f(GOps ops, int K)
{
    const int op = blockIdx.z;
    const float* __restrict__ A  = ops.A[op];
    const float* __restrict__ W  = ops.W[op];
    const float* __restrict__ Bi = ops.Bi[op];
    float* __restrict__       C  = ops.C[op];

    const int m0 = blockIdx.y << 6;
    const int n0 = blockIdx.x << 6;
    const int tid = threadIdx.x;
    const int tm  = tid >> 4;
    const int tn  = tid & 15;
    const int lr  = tid >> 2;
    const int lk4 = (tid & 3) << 2;

    __shared__ float As[16][64];
    __shared__ float Ws[16][64];

    float acc[4][4];
#pragma unroll
    for (int i = 0; i < 4; i++)
#pragma unroll
        for (int j = 0; j < 4; j++) acc[i][j] = 0.f;

    for (int k0 = 0; k0 < K; k0 += 16) {
        const float4 av = *(const float4*)(A + (long)(m0 + lr) * 512 + k0 + lk4);
        const float4 wv = *(const float4*)(W + (long)(n0 + lr) * K   + k0 + lk4);
        __syncthreads();
        As[lk4 + 0][lr] = av.x; As[lk4 + 1][lr] = av.y;
        As[lk4 + 2][lr] = av.z; As[lk4 + 3][lr] = av.w;
        Ws[lk4 + 0][lr] = wv.x; Ws[lk4 + 1][lr] = wv.y;
        Ws[lk4 + 2][lr] = wv.z; Ws[lk4 + 3][lr] = wv.w;
        __syncthreads();
#pragma unroll
        for (int kk = 0; kk < 16; kk++) {
            const float4 a4 = *(const float4*)(&As[kk][tm << 2]);
            const float4 b4 = *(const float4*)(&Ws[kk][tn << 2]);
            const float aa[4] = {a4.x, a4.y, a4.z, a4.w};
            const float bb[4] = {b4.x, b4.y, b4.z, b4.w};
#pragma unroll
            for (int i = 0; i < 4; i++)
#pragma unroll
                for (int j = 0; j < 4; j++)
                    acc[i][j] = fmaf(aa[i], bb[j], acc[i][j]);
        }
    }

    const float4 bv = *(const float4*)(Bi + n0 + (tn << 2));
    const float bArr[4] = {bv.x, bv.y, bv.z, bv.w};

#pragma unroll
    for (int i = 0; i < 4; i++) {
        float4 vo;
        vo.x = acc[i][0] + bArr[0]; vo.y = acc[i][1] + bArr[1];
        vo.z = acc[i][2] + bArr[2]; vo.w = acc[i][3] + bArr[3];
        *(float4*)(C + (long)(m0 + (tm << 2) + i) * 512 + n0 + (tn << 2)) = vo;
    }
}

// ---------------------------------------------------------------------------
// Fused per-chunk merge projections (K=64 GEMMs), both y0 and y1 in one launch.
// z in [0,16): z<8 -> y0 chunk z, z>=8 -> y1 chunk z-8.
// y0t: [B][C][S][K(160)][R]  (k-major over r: score lanes read 2x float4)
// y1p: [B][LQ][C][S][R]
// Note: a block covers one r (n0>>6) and all s = tn*4+j in 0..63.
// ---------------------------------------------------------------------------
__global__ __launch_bounds__(256) void y_proj(
    const float* __restrict__ x0, const float* __restrict__ wm0, const float* __restrict__ bm0,
    const float* __restrict__ x1, const float* __restrict__ wm1, const float* __restrict__ bm1,
    float* __restrict__ y0t, float* __restrict__ y1p)
{
    const int z   = blockIdx.z;
    const bool is1 = z >= 8;
    const int c   = is1 ? z - 8 : z;
    const float* A  = (is1 ? x1 : x0) + (c << 6);      // column slice, lda=512
    const float* W  = (is1 ? wm1 : wm0) + c * 32768;   // [512][64]
    const float* Bi = (is1 ? bm1 : bm0) + (c << 9);

    const int m0 = blockIdx.y << 6;
    const int n0 = blockIdx.x << 6;
    const int tid = threadIdx.x;
    const int tm  = tid >> 4;
    const int tn  = tid & 15;
    const int lr  = tid >> 2;
    const int lk4 = (tid & 3) << 2;

    __shared__ float As[16][64];
    __shared__ float Ws[16][64];

    float acc[4][4];
#pragma unroll
    for (int i = 0; i < 4; i++)
#pragma unroll
        for (int j = 0; j < 4; j++) acc[i][j] = 0.f;

    for (int k0 = 0; k0 < 64; k0 += 16) {
        const float4 av = *(const float4*)(A + (long)(m0 + lr) * 512 + k0 + lk4);
        const float4 wv = *(const float4*)(W + (long)(n0 + lr) * 64  + k0 + lk4);
        __syncthreads();
        As[lk4 + 0][lr] = av.x; As[lk4 + 1][lr] = av.y;
        As[lk4 + 2][lr] = av.z; As[lk4 + 3][lr] = av.w;
        Ws[lk4 + 0][lr] = wv.x; Ws[lk4 + 1][lr] = wv.y;
        Ws[lk4 + 2][lr] = wv.z; Ws[lk4 + 3][lr] = wv.w;
        __syncthreads();
#pragma unroll
        for (int kk = 0; kk < 16; kk++) {
            const float4 a4 = *(const float4*)(&As[kk][tm << 2]);
            const float4 b4 = *(const float4*)(&Ws[kk][tn << 2]);
            const float aa[4] = {a4.x, a4.y, a4.z, a4.w};
            const float bb[4] = {b4.x, b4.y, b4.z, b4.w};
#pragma unroll
            for (int i = 0; i < 4; i++)
#pragma unroll
                for (int j = 0; j < 4; j++)
                    acc[i][j] = fmaf(aa[i], bb[j], acc[i][j]);
        }
    }

    const float4 bv = *(const float4*)(Bi + n0 + (tn << 2));
    const float bArr[4] = {bv.x, bv.y, bv.z, bv.w};

    if (!is1) {
        // y0t[b][c][s][k][r] = acc + bias;  n = t = r*64+s
#pragma unroll
        for (int i = 0; i < 4; i++) {
            const int m    = m0 + (tm << 2) + i;
            const int bidx = m / 160;
            const int kk_  = m - bidx * 160;
            const long base = (((long)(bidx * 8 + c) * 64) * 160 + kk_) * 8;
#pragma unroll
            for (int j = 0; j < 4; j++) {
                const int n = n0 + (tn << 2) + j;
                const int s = n & 63, r = n >> 6;
                y0t[base + (long)s * 1280 + r] = acc[i][j] + bArr[j];
            }
        }
    } else {
#pragma unroll
        for (int j = 0; j < 4; j++) {
            const int n = n0 + (tn << 2) + j;
            const int s = n & 63, r = n >> 6;
            const long col = (long)(c << 9) + (s << 3) + r;
#pragma unroll
            for (int i = 0; i < 4; i++)
                y1p[(long)(m0 + (tm << 2) + i) * 4096 + col] = acc[i][j] + bArr[j];
        }
    }
}

// ---------------------------------------------------------------------------
// Per-(b, 8-q-tile, c) partial scores: num/sqrt(den) for one chunk.
// c = id&7 keeps one (b,c) y0t slab XCD-local; QT=8 halves y0t traffic.
// y0 loads: 2x float4 per s (contiguous [k][r]), prefetched one s ahead so
// L2 latency hides under the 8-q FMA/sqrt block.
// scores_p: [B][LQ][C][LK]
// ---------------------------------------------------------------------------
__global__ __launch_bounds__(192) void score_partial(
    const float* __restrict__ y1p, const float* __restrict__ y0t,
    const float* __restrict__ wbo, float* __restrict__ scores_p)
{
    const int id = blockIdx.x;
    const int c  = id & 7;
    const int j  = id >> 3;
    const int b  = j / 20;
    const int q0 = (j - b * 20) << 3;
    const int tid = threadIdx.x;
    const int k   = tid;

    __shared__ float y1c[8][512];   // [q][s*8+r] for chunk c

    const long y1base = (long)(b * LQ + q0) * 4096 + (c << 9);
    for (int t = tid; t < 1024; t += 192) {   // 1024 float4s = 8q x 512 floats
        const int qq = t >> 7, e = t & 127;
        ((float4*)&y1c[0][0])[t] =
            *(const float4*)(y1p + y1base + (long)qq * 4096 + (e << 2));
    }
    __syncthreads();
    if (k >= LK) return;

    const float* wb  = wbo + (c << 6);
    const float* ybc = y0t + (((long)(b * 8 + c) * 64) * 160 + k) * 8;

    float num[8], den[8];
#pragma unroll
    for (int q = 0; q < 8; q++) { num[q] = 0.f; den[q] = 0.f; }

    float4 a0 = *(const float4*)(ybc);
    float4 a1 = *(const float4*)(ybc + 4);
    for (int s = 0; s < 64; s++) {
        const float a[8] = {a0.x, a0.y, a0.z, a0.w, a1.x, a1.y, a1.z, a1.w};
        const int sn = (s + 1) & 63;          // last iter reloads s=0 (harmless)
        a0 = *(const float4*)(ybc + (long)sn * 1280);
        a1 = *(const float4*)(ybc + (long)sn * 1280 + 4);
        const float w = wb[s];
#pragma unroll
        for (int q = 0; q < 8; q++) {
            const float4 p0 = *(const float4*)(&y1c[q][s << 3]);
            const float4 p1 = *(const float4*)(&y1c[q][(s << 3) + 4]);
            float z = a[0] * p0.x;
            z = fmaf(a[1], p0.y, z); z = fmaf(a[2], p0.z, z); z = fmaf(a[3], p0.w, z);
            z = fmaf(a[4], p1.x, z); z = fmaf(a[5], p1.y, z);
            z = fmaf(a[6], p1.z, z); z = fmaf(a[7], p1.w, z);
            const float az = fabsf(z);
            num[q] = fmaf(copysignf(__builtin_amdgcn_sqrtf(az), z), w, num[q]);
            den[q] += az;
        }
    }
#pragma unroll
    for (int q = 0; q < 8; q++)
        scores_p[(((long)(b * LQ + q0 + q)) * 8 + c) * 160 + k] =
            num[q] / fmaxf(__builtin_amdgcn_sqrtf(den[q]), 1e-12f);
}

// ---------------------------------------------------------------------------
// Sum partials over c, softmax over k, att@vv, write attedT [B][512][LQ]
// (= row-major input of the final linear after the torch transpose/view).
// b_bo dropped: softmax is shift-invariant.
// ---------------------------------------------------------------------------
__global__ __launch_bounds__(256) void softmax_attv(
    const float* __restrict__ scores_p, const float* __restrict__ vv,
    float* __restrict__ attedT)
{
    const int b  = blockIdx.y;
    const int q0 = blockIdx.x << 2;
    const int tid = threadIdx.x;

    __shared__ float scs[4][160];
    __shared__ float invd[4];

    for (int t = tid; t < 640; t += 256) {
        const int q = t / 160;
        const int k = t - q * 160;
        const float* sp = scores_p + ((long)(b * LQ + q0 + q)) * 1280 + k;
        float s = 0.f;
#pragma unroll
        for (int c = 0; c < 8; c++) s += sp[c * 160];
        scs[q][k] = s;
    }
    __syncthreads();

    const int w    = tid >> 6;
    const int lane = tid & 63;
    {
        const int q = w;
        float m = -1e30f;
        for (int kk = lane; kk < LK; kk += 64) m = fmaxf(m, scs[q][kk]);
#pragma unroll
        for (int off = 32; off; off >>= 1) m = fmaxf(m, __shfl_xor(m, off, 64));
        float sum = 0.f;
        for (int kk = lane; kk < LK; kk += 64) {
            const float e = __expf(scs[q][kk] - m);
            scs[q][kk] = e;
            sum += e;
        }
#pragma unroll
        for (int off = 32; off; off >>= 1) sum += __shfl_xor(sum, off, 64);
        if (lane == 0) invd[q] = 1.f / sum;
    }
    __syncthreads();

    float acc[2][4] = {{0.f,0.f,0.f,0.f},{0.f,0.f,0.f,0.f}};
    const float* vb = vv + (long)b * (LK * 512);
    for (int kk = 0; kk < LK; kk++) {
        const float* vr = vb + kk * 512;
        const float p0 = scs[0][kk], p1 = scs[1][kk];
        const float p2 = scs[2][kk], p3 = scs[3][kk];
        const float v0 = vr[tid], v1 = vr[tid + 256];
        acc[0][0] = fmaf(p0, v0, acc[0][0]); acc[0][1] = fmaf(p1, v0, acc[0][1]);
        acc[0][2] = fmaf(p2, v0, acc[0][2]); acc[0][3] = fmaf(p3, v0, acc[0][3]);
        acc[1][0] = fmaf(p0, v1, acc[1][0]); acc[1][1] = fmaf(p1, v1, acc[1][1]);
        acc[1][2] = fmaf(p2, v1, acc[1][2]); acc[1][3] = fmaf(p3, v1, acc[1][3]);
    }
#pragma unroll
    for (int j = 0; j < 2; j++) {
        const int h = tid + (j << 8);
#pragma unroll
        for (int q = 0; q < 4; q++)
            attedT[((long)b * 512 + h) * 160 + q0 + q] = acc[j][q] * invd[q];
    }
}

// ---------------------------------------------------------------------------
extern "C" void kernel_launch(void* const* d_in, const int* in_sizes, int n_in,
                              void* d_out, int out_size, void* d_ws, size_t ws_size,
                              hipStream_t stream) {
    const float* v    = (const float*)d_in[0];
    const float* kin  = (const float*)d_in[1];
    const float* q    = (const float*)d_in[2];
    const float* w_v  = (const float*)d_in[3];
    const float* b_v  = (const float*)d_in[4];
    const float* w_k  = (const float*)d_in[5];
    const float* b_k  = (const float*)d_in[6];
    const float* w_q  = (const float*)d_in[7];
    const float* b_q  = (const float*)d_in[8];
    const float* w0   = (const float*)d_in[9];
    const float* b0   = (const float*)d_in[10];
    const float* w1   = (const float*)d_in[11];
    const float* b1   = (const float*)d_in[12];
    const float* wm0  = (const float*)d_in[13];
    const float* bm0  = (const float*)d_in[14];
    const float* wm1  = (const float*)d_in[15];
    const float* bm1  = (const float*)d_in[16];
    const float* w_bo = (const float*)d_in[17];
    (void)d_in[18];  // b_bo unused: softmax is shift-invariant
    const float* w_m  = (const float*)d_in[19];
    const float* b_m  = (const float*)d_in[20];

    float* ws       = (float*)d_ws;
    float* vv       = ws;                  // 655360
    float* kk       = ws + 655360;         // 655360
    float* qq       = ws + 1310720;        // 655360
    float* x0       = ws + 1966080;        // 655360
    float* x1       = ws + 2621440;        // 655360
    float* y1p      = ws + 3276800;        // 5242880  [B][LQ][c][s][r]
    float* y0t      = ws + 8519680;        // 5242880  [B][c][s][k][r]
    float* attedT   = ws + 13762560;       // 655360   [B][512][LQ]
    float* scores_p = ws + 655360;         // 1638400, aliases kk/qq/x0 (dead by then)

    GOps oA;
    oA.A[0] = v;   oA.W[0] = w_v; oA.Bi[0] = b_v; oA.C[0] = vv;
    oA.A[1] = kin; oA.W[1] = w_k; oA.Bi[1] = b_k; oA.C[1] = kk;
    oA.A[2] = q;   oA.W[2] = w_q; oA.Bi[2] = b_q; oA.C[2] = qq;
    hipLaunchKernelGGL(gemm_f, dim3(8, 20, 3), dim3(256), 0, stream, oA, 512);

    GOps oB;
    oB.A[0] = kk; oB.W[0] = w0; oB.Bi[0] = b0; oB.C[0] = x0;
    oB.A[1] = qq; oB.W[1] = w1; oB.Bi[1] = b1; oB.C[1] = x1;
    oB.A[2] = nullptr; oB.W[2] = nullptr; oB.Bi[2] = nullptr; oB.C[2] = nullptr;
    hipLaunchKernelGGL(gemm_f, dim3(8, 20, 2), dim3(256), 0, stream, oB, 512);

    hipLaunchKernelGGL(y_proj, dim3(8, 20, 16), dim3(256), 0, stream,
                       x0, wm0, bm0, x1, wm1, bm1, y0t, y1p);

    hipLaunchKernelGGL(score_partial, dim3(1280), dim3(192), 0, stream,
                       y1p, y0t, w_bo, scores_p);

    hipLaunchKernelGGL(softmax_attv, dim3(40, 8), dim3(256), 0, stream,
                       scores_p, vv, attedT);

    GOps oF;
    oF.A[0] = attedT; oF.W[0] = w_m; oF.Bi[0] = b_m; oF.C[0] = (float*)d_out;
    oF.A[1] = nullptr; oF.W[1] = nullptr; oF.Bi[1] = nullptr; oF.C[1] = nullptr;
    oF.A[2] = nullptr; oF.W[2] = nullptr; oF.Bi[2] = nullptr; oF.C[2] = nullptr;
    hipLaunchKernelGGL(gemm_f, dim3(8, 20, 1), dim3(256), 0, stream, oF, 512);
}

// Round 6
// 307.810 us; speedup vs baseline: 2.4158x; 1.3744x over previous
//
#include <hip/hip_runtime.h>
#include <hip/hip_bf16.h>

#define B_  8
#define LQ  160
#define LK  160

// ---------------------------------------------------------------------------
// Multi-op fp32 GEMM, full K, no atomics.
// C[m,n] = sum_k A[m,k]*W[n,k] + bias[n]; A [1280,512] lda=512, W [N=512,K=512],
// C ld 512. blockIdx.z selects op. 64x64 tile, 256 threads, 4x4 micro.
// ---------------------------------------------------------------------------
struct GOps {
    const float* A[3];
    const float* W[3];
    const float* Bi[3];
    float*       C[3];
};

__global__ __launch_bounds__(256) void gemm_f(GOps ops, int K)
{
    const int op = blockIdx.z;
    const float* __restrict__ A  = ops.A[op];
    const float* __restrict__ W  = ops.W[op];
    const float* __restrict__ Bi = ops.Bi[op];
    float* __restrict__       C  = ops.C[op];

    const int m0 = blockIdx.y << 6;
    const int n0 = blockIdx.x << 6;
    const int tid = threadIdx.x;
    const int tm  = tid >> 4;
    const int tn  = tid & 15;
    const int lr  = tid >> 2;
    const int lk4 = (tid & 3) << 2;

    __shared__ float As[16][64];
    __shared__ float Ws[16][64];

    float acc[4][4];
#pragma unroll
    for (int i = 0; i < 4; i++)
#pragma unroll
        for (int j = 0; j < 4; j++) acc[i][j] = 0.f;

    for (int k0 = 0; k0 < K; k0 += 16) {
        const float4 av = *(const float4*)(A + (long)(m0 + lr) * 512 + k0 + lk4);
        const float4 wv = *(const float4*)(W + (long)(n0 + lr) * K   + k0 + lk4);
        __syncthreads();
        As[lk4 + 0][lr] = av.x; As[lk4 + 1][lr] = av.y;
        As[lk4 + 2][lr] = av.z; As[lk4 + 3][lr] = av.w;
        Ws[lk4 + 0][lr] = wv.x; Ws[lk4 + 1][lr] = wv.y;
        Ws[lk4 + 2][lr] = wv.z; Ws[lk4 + 3][lr] = wv.w;
        __syncthreads();
#pragma unroll
        for (int kk = 0; kk < 16; kk++) {
            const float4 a4 = *(const float4*)(&As[kk][tm << 2]);
            const float4 b4 = *(const float4*)(&Ws[kk][tn << 2]);
            const float aa[4] = {a4.x, a4.y, a4.z, a4.w};
            const float bb[4] = {b4.x, b4.y, b4.z, b4.w};
#pragma unroll
            for (int i = 0; i < 4; i++)
#pragma unroll
                for (int j = 0; j < 4; j++)
                    acc[i][j] = fmaf(aa[i], bb[j], acc[i][j]);
        }
    }

    const float4 bv = *(const float4*)(Bi + n0 + (tn << 2));
    const float bArr[4] = {bv.x, bv.y, bv.z, bv.w};

#pragma unroll
    for (int i = 0; i < 4; i++) {
        float4 vo;
        vo.x = acc[i][0] + bArr[0]; vo.y = acc[i][1] + bArr[1];
        vo.z = acc[i][2] + bArr[2]; vo.w = acc[i][3] + bArr[3];
        *(float4*)(C + (long)(m0 + (tm << 2) + i) * 512 + n0 + (tn << 2)) = vo;
    }
}

// ---------------------------------------------------------------------------
// Fused per-chunk merge projections (K=64 GEMMs), both y0 and y1 in one launch.
// z in [0,16): z<8 -> y0 chunk z, z>=8 -> y1 chunk z-8.
//
// y1 (is1): natural N order; layout y1p[b][m][c][r][s] -> col = c*512 + n.
//   Epilogue = plain float4 stores (contiguous 256B segments). No amplification.
// y0: remapped N order: block covers s in [s0,s0+8) x all r (ln -> t = (ln&7)*64
//   + s0 + (ln>>3)). Output tile staged via 16KB LDS transpose, then written as
//   512-float contiguous runs per s into y0t[b][c][s][k][r] (piecewise split at
//   the b-boundary since 64 does not divide 160).
// ---------------------------------------------------------------------------
__global__ __launch_bounds__(256) void y_proj(
    const float* __restrict__ x0, const float* __restrict__ wm0, const float* __restrict__ bm0,
    const float* __restrict__ x1, const float* __restrict__ wm1, const float* __restrict__ bm1,
    float* __restrict__ y0t, float* __restrict__ y1p)
{
    const int z   = blockIdx.z;
    const bool is1 = z >= 8;
    const int c   = is1 ? z - 8 : z;
    const float* A  = (is1 ? x1 : x0) + (c << 6);      // column slice, lda=512
    const float* W  = (is1 ? wm1 : wm0) + c * 32768;   // [512][64]
    const float* Bi = (is1 ? bm1 : bm0) + (c << 9);

    const int m0 = blockIdx.y << 6;
    const int bx  = blockIdx.x;
    const int n0 = bx << 6;            // natural (y1)
    const int s0 = bx << 3;            // remapped (y0)
    const int tid = threadIdx.x;
    const int tm  = tid >> 4;
    const int tn  = tid & 15;
    const int lr  = tid >> 2;
    const int lk4 = (tid & 3) << 2;

    __shared__ float As[16][64];
    __shared__ float Ws[16][64];
    __shared__ float outT[4096];       // [s8][k8][r] staging for y0

    float acc[4][4];
#pragma unroll
    for (int i = 0; i < 4; i++)
#pragma unroll
        for (int j = 0; j < 4; j++) acc[i][j] = 0.f;

    // W row for logical column lr
    const int wrow = is1 ? (n0 + lr) : (((lr & 7) << 6) + s0 + (lr >> 3));

    for (int k0 = 0; k0 < 64; k0 += 16) {
        const float4 av = *(const float4*)(A + (long)(m0 + lr) * 512 + k0 + lk4);
        const float4 wv = *(const float4*)(W + (long)wrow * 64 + k0 + lk4);
        __syncthreads();
        As[lk4 + 0][lr] = av.x; As[lk4 + 1][lr] = av.y;
        As[lk4 + 2][lr] = av.z; As[lk4 + 3][lr] = av.w;
        Ws[lk4 + 0][lr] = wv.x; Ws[lk4 + 1][lr] = wv.y;
        Ws[lk4 + 2][lr] = wv.z; Ws[lk4 + 3][lr] = wv.w;
        __syncthreads();
#pragma unroll
        for (int kk = 0; kk < 16; kk++) {
            const float4 a4 = *(const float4*)(&As[kk][tm << 2]);
            const float4 b4 = *(const float4*)(&Ws[kk][tn << 2]);
            const float aa[4] = {a4.x, a4.y, a4.z, a4.w};
            const float bb[4] = {b4.x, b4.y, b4.z, b4.w};
#pragma unroll
            for (int i = 0; i < 4; i++)
#pragma unroll
                for (int j = 0; j < 4; j++)
                    acc[i][j] = fmaf(aa[i], bb[j], acc[i][j]);
        }
    }

    if (is1) {
        const float4 bv = *(const float4*)(Bi + n0 + (tn << 2));
        const float bArr[4] = {bv.x, bv.y, bv.z, bv.w};
#pragma unroll
        for (int i = 0; i < 4; i++) {
            const int m = m0 + (tm << 2) + i;
            float4 vo;
            vo.x = acc[i][0] + bArr[0]; vo.y = acc[i][1] + bArr[1];
            vo.z = acc[i][2] + bArr[2]; vo.w = acc[i][3] + bArr[3];
            *(float4*)(y1p + (long)m * 4096 + (c << 9) + n0 + (tn << 2)) = vo;
        }
    } else {
        // bias for logical column ln = tn*4+j: t = (ln&7)*64 + s0 + (ln>>3)
        float bArr[4];
#pragma unroll
        for (int j = 0; j < 4; j++) {
            const int ln = (tn << 2) + j;
            bArr[j] = Bi[((ln & 7) << 6) + s0 + (ln >> 3)];
        }
        __syncthreads();   // protect outT vs Ws-phase stragglers (none, but cheap)
#pragma unroll
        for (int i = 0; i < 4; i++) {
            const int k8 = (tm << 2) + i;
#pragma unroll
            for (int j = 0; j < 4; j++) {
                const int ln = (tn << 2) + j;
                outT[((ln >> 3) << 9) + (k8 << 3) + (ln & 7)] = acc[i][j] + bArr[j];
            }
        }
        __syncthreads();
        // write 8 runs of 512 contiguous floats (one per s8), 2 runs per pass
#pragma unroll
        for (int p = 0; p < 4; p++) {
            const int s8  = (p << 1) + (tid >> 7);
            const int u4  = tid & 127;          // float4 index within the run
            const int k8  = u4 >> 1;
            const int r   = (u4 & 1) << 2;
            const int m   = m0 + k8;
            const int bidx = m / 160;
            const int kmod = m - bidx * 160;
            const int s   = s0 + s8;
            float4* dst = (float4*)(y0t +
                (((long)(bidx * 8 + c) * 64 + s) * 160 + kmod) * 8 + r);
            *dst = *(const float4*)&outT[(s8 << 9) + (u4 << 2)];
        }
    }
}

// ---------------------------------------------------------------------------
// Per-(b, 8-q-tile, c) partial scores: num/sqrt(den) for one chunk.
// c = id&7 keeps one (b,c) y0t slab XCD-local; QT=8.
// y0 loads: 2x float4 per s (contiguous [k][r]), prefetched one s ahead.
// y1p is [b][m][c][r][s]; transposed into LDS [q][s*8+r] at stage time.
// scores_p: [B][LQ][C][LK]
// ---------------------------------------------------------------------------
__global__ __launch_bounds__(192) void score_partial(
    const float* __restrict__ y1p, const float* __restrict__ y0t,
    const float* __restrict__ wbo, float* __restrict__ scores_p)
{
    const int id = blockIdx.x;
    const int c  = id & 7;
    const int j  = id >> 3;
    const int b  = j / 20;
    const int q0 = (j - b * 20) << 3;
    const int tid = threadIdx.x;
    const int k   = tid;

    __shared__ float y1c[8][512];   // [q][s*8+r] for chunk c

    const long y1base = (long)(b * LQ + q0) * 4096 + (c << 9);
    for (int t = tid; t < 1024; t += 192) {   // 1024 float4s = 8q x 512 floats
        const int qq = t >> 7, e = t & 127;
        const float4 v =
            *(const float4*)(y1p + y1base + (long)qq * 4096 + (e << 2));
        const int r  = e >> 4;
        const int s4 = (e & 15) << 2;
        y1c[qq][(s4 + 0) * 8 + r] = v.x;
        y1c[qq][(s4 + 1) * 8 + r] = v.y;
        y1c[qq][(s4 + 2) * 8 + r] = v.z;
        y1c[qq][(s4 + 3) * 8 + r] = v.w;
    }
    __syncthreads();
    if (k >= LK) return;

    const float* wb  = wbo + (c << 6);
    const float* ybc = y0t + (((long)(b * 8 + c) * 64) * 160 + k) * 8;

    float num[8], den[8];
#pragma unroll
    for (int q = 0; q < 8; q++) { num[q] = 0.f; den[q] = 0.f; }

    float4 a0 = *(const float4*)(ybc);
    float4 a1 = *(const float4*)(ybc + 4);
    for (int s = 0; s < 64; s++) {
        const float a[8] = {a0.x, a0.y, a0.z, a0.w, a1.x, a1.y, a1.z, a1.w};
        const int sn = (s + 1) & 63;          // last iter reloads s=0 (harmless)
        a0 = *(const float4*)(ybc + (long)sn * 1280);
        a1 = *(const float4*)(ybc + (long)sn * 1280 + 4);
        const float w = wb[s];
#pragma unroll
        for (int q = 0; q < 8; q++) {
            const float4 p0 = *(const float4*)(&y1c[q][s << 3]);
            const float4 p1 = *(const float4*)(&y1c[q][(s << 3) + 4]);
            float z = a[0] * p0.x;
            z = fmaf(a[1], p0.y, z); z = fmaf(a[2], p0.z, z); z = fmaf(a[3], p0.w, z);
            z = fmaf(a[4], p1.x, z); z = fmaf(a[5], p1.y, z);
            z = fmaf(a[6], p1.z, z); z = fmaf(a[7], p1.w, z);
            const float az = fabsf(z);
            num[q] = fmaf(copysignf(__builtin_amdgcn_sqrtf(az), z), w, num[q]);
            den[q] += az;
        }
    }
#pragma unroll
    for (int q = 0; q < 8; q++)
        scores_p[(((long)(b * LQ + q0 + q)) * 8 + c) * 160 + k] =
            num[q] / fmaxf(__builtin_amdgcn_sqrtf(den[q]), 1e-12f);
}

// ---------------------------------------------------------------------------
// Sum partials over c, softmax over k, att@vv, write attedT [B][512][LQ]
// (= row-major input of the final linear after the torch transpose/view).
// b_bo dropped: softmax is shift-invariant.
// ---------------------------------------------------------------------------
__global__ __launch_bounds__(256) void softmax_attv(
    const float* __restrict__ scores_p, const float* __restrict__ vv,
    float* __restrict__ attedT)
{
    const int b  = blockIdx.y;
    const int q0 = blockIdx.x << 2;
    const int tid = threadIdx.x;

    __shared__ float scs[4][160];
    __shared__ float invd[4];

    for (int t = tid; t < 640; t += 256) {
        const int q = t / 160;
        const int k = t - q * 160;
        const float* sp = scores_p + ((long)(b * LQ + q0 + q)) * 1280 + k;
        float s = 0.f;
#pragma unroll
        for (int c = 0; c < 8; c++) s += sp[c * 160];
        scs[q][k] = s;
    }
    __syncthreads();

    const int w    = tid >> 6;
    const int lane = tid & 63;
    {
        const int q = w;
        float m = -1e30f;
        for (int kk = lane; kk < LK; kk += 64) m = fmaxf(m, scs[q][kk]);
#pragma unroll
        for (int off = 32; off; off >>= 1) m = fmaxf(m, __shfl_xor(m, off, 64));
        float sum = 0.f;
        for (int kk = lane; kk < LK; kk += 64) {
            const float e = __expf(scs[q][kk] - m);
            scs[q][kk] = e;
            sum += e;
        }
#pragma unroll
        for (int off = 32; off; off >>= 1) sum += __shfl_xor(sum, off, 64);
        if (lane == 0) invd[q] = 1.f / sum;
    }
    __syncthreads();

    float acc[2][4] = {{0.f,0.f,0.f,0.f},{0.f,0.f,0.f,0.f}};
    const float* vb = vv + (long)b * (LK * 512);
    for (int kk = 0; kk < LK; kk++) {
        const float* vr = vb + kk * 512;
        const float p0 = scs[0][kk], p1 = scs[1][kk];
        const float p2 = scs[2][kk], p3 = scs[3][kk];
        const float v0 = vr[tid], v1 = vr[tid + 256];
        acc[0][0] = fmaf(p0, v0, acc[0][0]); acc[0][1] = fmaf(p1, v0, acc[0][1]);
        acc[0][2] = fmaf(p2, v0, acc[0][2]); acc[0][3] = fmaf(p3, v0, acc[0][3]);
        acc[1][0] = fmaf(p0, v1, acc[1][0]); acc[1][1] = fmaf(p1, v1, acc[1][1]);
        acc[1][2] = fmaf(p2, v1, acc[1][2]); acc[1][3] = fmaf(p3, v1, acc[1][3]);
    }
#pragma unroll
    for (int j = 0; j < 2; j++) {
        const int h = tid + (j << 8);
#pragma unroll
        for (int q = 0; q < 4; q++)
            attedT[((long)b * 512 + h) * 160 + q0 + q] = acc[j][q] * invd[q];
    }
}

// ---------------------------------------------------------------------------
extern "C" void kernel_launch(void* const* d_in, const int* in_sizes, int n_in,
                              void* d_out, int out_size, void* d_ws, size_t ws_size,
                              hipStream_t stream) {
    const float* v    = (const float*)d_in[0];
    const float* kin  = (const float*)d_in[1];
    const float* q    = (const float*)d_in[2];
    const float* w_v  = (const float*)d_in[3];
    const float* b_v  = (const float*)d_in[4];
    const float* w_k  = (const float*)d_in[5];
    const float* b_k  = (const float*)d_in[6];
    const float* w_q  = (const float*)d_in[7];
    const float* b_q  = (const float*)d_in[8];
    const float* w0   = (const float*)d_in[9];
    const float* b0   = (const float*)d_in[10];
    const float* w1   = (const float*)d_in[11];
    const float* b1   = (const float*)d_in[12];
    const float* wm0  = (const float*)d_in[13];
    const float* bm0  = (const float*)d_in[14];
    const float* wm1  = (const float*)d_in[15];
    const float* bm1  = (const float*)d_in[16];
    const float* w_bo = (const float*)d_in[17];
    (void)d_in[18];  // b_bo unused: softmax is shift-invariant
    const float* w_m  = (const float*)d_in[19];
    const float* b_m  = (const float*)d_in[20];

    float* ws       = (float*)d_ws;
    float* vv       = ws;                  // 655360
    float* kk       = ws + 655360;         // 655360
    float* qq       = ws + 1310720;        // 655360
    float* x0       = ws + 1966080;        // 655360
    float* x1       = ws + 2621440;        // 655360
    float* y1p      = ws + 3276800;        // 5242880  [B][LQ][c][r][s]
    float* y0t      = ws + 8519680;        // 5242880  [B][c][s][k][r]
    float* attedT   = ws + 13762560;       // 655360   [B][512][LQ]
    float* scores_p = ws + 655360;         // 1638400, aliases kk/qq/x0 (dead by then)

    GOps oA;
    oA.A[0] = v;   oA.W[0] = w_v; oA.Bi[0] = b_v; oA.C[0] = vv;
    oA.A[1] = kin; oA.W[1] = w_k; oA.Bi[1] = b_k; oA.C[1] = kk;
    oA.A[2] = q;   oA.W[2] = w_q; oA.Bi[2] = b_q; oA.C[2] = qq;
    hipLaunchKernelGGL(gemm_f, dim3(8, 20, 3), dim3(256), 0, stream, oA, 512);

    GOps oB;
    oB.A[0] = kk; oB.W[0] = w0; oB.Bi[0] = b0; oB.C[0] = x0;
    oB.A[1] = qq; oB.W[1] = w1; oB.Bi[1] = b1; oB.C[1] = x1;
    oB.A[2] = nullptr; oB.W[2] = nullptr; oB.Bi[2] = nullptr; oB.C[2] = nullptr;
    hipLaunchKernelGGL(gemm_f, dim3(8, 20, 2), dim3(256), 0, stream, oB, 512);

    hipLaunchKernelGGL(y_proj, dim3(8, 20, 16), dim3(256), 0, stream,
                       x0, wm0, bm0, x1, wm1, bm1, y0t, y1p);

    hipLaunchKernelGGL(score_partial, dim3(1280), dim3(192), 0, stream,
                       y1p, y0t, w_bo, scores_p);

    hipLaunchKernelGGL(softmax_attv, dim3(40, 8), dim3(256), 0, stream,
                       scores_p, vv, attedT);

    GOps oF;
    oF.A[0] = attedT; oF.W[0] = w_m; oF.Bi[0] = b_m; oF.C[0] = (float*)d_out;
    oF.A[1] = nullptr; oF.W[1] = nullptr; oF.Bi[1] = nullptr; oF.C[1] = nullptr;
    oF.A[2] = nullptr; oF.W[2] = nullptr; oF.Bi[2] = nullptr; oF.C[2] = nullptr;
    hipLaunchKernelGGL(gemm_f, dim3(8, 20, 1), dim3(256), 0, stream, oF, 512);
}

// Round 7
// 296.740 us; speedup vs baseline: 2.5059x; 1.0373x over previous
//
#include <hip/hip_runtime.h>
#include <hip/hip_bf16.h>

#define B_  8
#define LQ  160
#define LK  160

// ---------------------------------------------------------------------------
// Multi-op fp32 GEMM, full K, no atomics, software-pipelined global loads:
// next tile's loads issue right after the barrier, overlapping the compute.
// C[m,n] = sum_k A[m,k]*W[n,k] + bias[n]; A [1280,512] lda=512, W [N,K], C ld 512.
// ---------------------------------------------------------------------------
struct GOps {
    const float* A[3];
    const float* W[3];
    const float* Bi[3];
    float*       C[3];
};

__global__ __launch_bounds__(256) void gemm_f(GOps ops, int K)
{
    const int op = blockIdx.z;
    const float* __restrict__ A  = ops.A[op];
    const float* __restrict__ W  = ops.W[op];
    const float* __restrict__ Bi = ops.Bi[op];
    float* __restrict__       C  = ops.C[op];

    const int m0 = blockIdx.y << 6;
    const int n0 = blockIdx.x << 6;
    const int tid = threadIdx.x;
    const int tm  = tid >> 4;
    const int tn  = tid & 15;
    const int lr  = tid >> 2;
    const int lk4 = (tid & 3) << 2;

    __shared__ float As[16][64];
    __shared__ float Ws[16][64];

    float acc[4][4];
#pragma unroll
    for (int i = 0; i < 4; i++)
#pragma unroll
        for (int j = 0; j < 4; j++) acc[i][j] = 0.f;

    const float* Arow = A + (long)(m0 + lr) * 512 + lk4;
    const float* Wrow = W + (long)(n0 + lr) * K + lk4;
    float4 av = *(const float4*)(Arow);
    float4 wv = *(const float4*)(Wrow);

    for (int k0 = 0; k0 < K; k0 += 16) {
        __syncthreads();
        As[lk4 + 0][lr] = av.x; As[lk4 + 1][lr] = av.y;
        As[lk4 + 2][lr] = av.z; As[lk4 + 3][lr] = av.w;
        Ws[lk4 + 0][lr] = wv.x; Ws[lk4 + 1][lr] = wv.y;
        Ws[lk4 + 2][lr] = wv.z; Ws[lk4 + 3][lr] = wv.w;
        __syncthreads();
        if (k0 + 16 < K) {                       // prefetch next tile (hides latency)
            av = *(const float4*)(Arow + k0 + 16);
            wv = *(const float4*)(Wrow + k0 + 16);
        }
#pragma unroll
        for (int kk = 0; kk < 16; kk++) {
            const float4 a4 = *(const float4*)(&As[kk][tm << 2]);
            const float4 b4 = *(const float4*)(&Ws[kk][tn << 2]);
            const float aa[4] = {a4.x, a4.y, a4.z, a4.w};
            const float bb[4] = {b4.x, b4.y, b4.z, b4.w};
#pragma unroll
            for (int i = 0; i < 4; i++)
#pragma unroll
                for (int j = 0; j < 4; j++)
                    acc[i][j] = fmaf(aa[i], bb[j], acc[i][j]);
        }
    }

    const float4 bv = *(const float4*)(Bi + n0 + (tn << 2));
    const float bArr[4] = {bv.x, bv.y, bv.z, bv.w};

#pragma unroll
    for (int i = 0; i < 4; i++) {
        float4 vo;
        vo.x = acc[i][0] + bArr[0]; vo.y = acc[i][1] + bArr[1];
        vo.z = acc[i][2] + bArr[2]; vo.w = acc[i][3] + bArr[3];
        *(float4*)(C + (long)(m0 + (tm << 2) + i) * 512 + n0 + (tn << 2)) = vo;
    }
}

// ---------------------------------------------------------------------------
// Fused per-chunk merge projections (K=64 GEMMs), both y0 and y1 in one launch.
// Software-pipelined like gemm_f. z<8 -> y0 chunk z, z>=8 -> y1 chunk z-8.
// y1: y1p[b][m][c][r][s]; coalesced float4 epilogue.
// y0: remapped N (block = 8 s x 8 r), LDS-transposed, written as contiguous
//     512-float runs per s into y0t[b][c][s][k][r].
// ---------------------------------------------------------------------------
__global__ __launch_bounds__(256) void y_proj(
    const float* __restrict__ x0, const float* __restrict__ wm0, const float* __restrict__ bm0,
    const float* __restrict__ x1, const float* __restrict__ wm1, const float* __restrict__ bm1,
    float* __restrict__ y0t, float* __restrict__ y1p)
{
    const int z   = blockIdx.z;
    const bool is1 = z >= 8;
    const int c   = is1 ? z - 8 : z;
    const float* A  = (is1 ? x1 : x0) + (c << 6);      // column slice, lda=512
    const float* W  = (is1 ? wm1 : wm0) + c * 32768;   // [512][64]
    const float* Bi = (is1 ? bm1 : bm0) + (c << 9);

    const int m0 = blockIdx.y << 6;
    const int bx  = blockIdx.x;
    const int n0 = bx << 6;            // natural (y1)
    const int s0 = bx << 3;            // remapped (y0)
    const int tid = threadIdx.x;
    const int tm  = tid >> 4;
    const int tn  = tid & 15;
    const int lr  = tid >> 2;
    const int lk4 = (tid & 3) << 2;

    __shared__ float As[16][64];
    __shared__ float Ws[16][64];
    __shared__ float outT[4096];       // [s8][k8][r] staging for y0

    float acc[4][4];
#pragma unroll
    for (int i = 0; i < 4; i++)
#pragma unroll
        for (int j = 0; j < 4; j++) acc[i][j] = 0.f;

    // W row for logical column lr
    const int wrow = is1 ? (n0 + lr) : (((lr & 7) << 6) + s0 + (lr >> 3));
    const float* Arow = A + (long)(m0 + lr) * 512 + lk4;
    const float* Wrow = W + (long)wrow * 64 + lk4;
    float4 av = *(const float4*)(Arow);
    float4 wv = *(const float4*)(Wrow);

    for (int k0 = 0; k0 < 64; k0 += 16) {
        __syncthreads();
        As[lk4 + 0][lr] = av.x; As[lk4 + 1][lr] = av.y;
        As[lk4 + 2][lr] = av.z; As[lk4 + 3][lr] = av.w;
        Ws[lk4 + 0][lr] = wv.x; Ws[lk4 + 1][lr] = wv.y;
        Ws[lk4 + 2][lr] = wv.z; Ws[lk4 + 3][lr] = wv.w;
        __syncthreads();
        if (k0 + 16 < 64) {
            av = *(const float4*)(Arow + k0 + 16);
            wv = *(const float4*)(Wrow + k0 + 16);
        }
#pragma unroll
        for (int kk = 0; kk < 16; kk++) {
            const float4 a4 = *(const float4*)(&As[kk][tm << 2]);
            const float4 b4 = *(const float4*)(&Ws[kk][tn << 2]);
            const float aa[4] = {a4.x, a4.y, a4.z, a4.w};
            const float bb[4] = {b4.x, b4.y, b4.z, b4.w};
#pragma unroll
            for (int i = 0; i < 4; i++)
#pragma unroll
                for (int j = 0; j < 4; j++)
                    acc[i][j] = fmaf(aa[i], bb[j], acc[i][j]);
        }
    }

    if (is1) {
        const float4 bv = *(const float4*)(Bi + n0 + (tn << 2));
        const float bArr[4] = {bv.x, bv.y, bv.z, bv.w};
#pragma unroll
        for (int i = 0; i < 4; i++) {
            const int m = m0 + (tm << 2) + i;
            float4 vo;
            vo.x = acc[i][0] + bArr[0]; vo.y = acc[i][1] + bArr[1];
            vo.z = acc[i][2] + bArr[2]; vo.w = acc[i][3] + bArr[3];
            *(float4*)(y1p + (long)m * 4096 + (c << 9) + n0 + (tn << 2)) = vo;
        }
    } else {
        // bias for logical column ln = tn*4+j: t = (ln&7)*64 + s0 + (ln>>3)
        float bArr[4];
#pragma unroll
        for (int j = 0; j < 4; j++) {
            const int ln = (tn << 2) + j;
            bArr[j] = Bi[((ln & 7) << 6) + s0 + (ln >> 3)];
        }
        __syncthreads();
#pragma unroll
        for (int i = 0; i < 4; i++) {
            const int k8 = (tm << 2) + i;
#pragma unroll
            for (int j = 0; j < 4; j++) {
                const int ln = (tn << 2) + j;
                outT[((ln >> 3) << 9) + (k8 << 3) + (ln & 7)] = acc[i][j] + bArr[j];
            }
        }
        __syncthreads();
        // write 8 runs of 512 contiguous floats (one per s8), 2 runs per pass
#pragma unroll
        for (int p = 0; p < 4; p++) {
            const int s8  = (p << 1) + (tid >> 7);
            const int u4  = tid & 127;          // float4 index within the run
            const int k8  = u4 >> 1;
            const int r   = (u4 & 1) << 2;
            const int m   = m0 + k8;
            const int bidx = m / 160;
            const int kmod = m - bidx * 160;
            const int s   = s0 + s8;
            float4* dst = (float4*)(y0t +
                (((long)(bidx * 8 + c) * 64 + s) * 160 + kmod) * 8 + r);
            *dst = *(const float4*)&outT[(s8 << 9) + (u4 << 2)];
        }
    }
}

// ---------------------------------------------------------------------------
// Per-(b, 4-q-tile, c) partial scores. QT=4: grid 2560 blocks -> 10 blocks/CU
// (94% occupancy cap). c = id&7 keeps one (b,c) y0t slab XCD-local.
// y0 loads: 2x float4 per s (contiguous [k][r]), prefetched one s ahead.
// y1p is [b][m][c][r][s]; transposed into LDS [q][s*8+r] at stage time.
// scores_p: [B][LQ][C][LK]
// ---------------------------------------------------------------------------
__global__ __launch_bounds__(192) void score_partial(
    const float* __restrict__ y1p, const float* __restrict__ y0t,
    const float* __restrict__ wbo, float* __restrict__ scores_p)
{
    const int id = blockIdx.x;
    const int c  = id & 7;
    const int j  = id >> 3;
    const int b  = j / 40;
    const int q0 = (j - b * 40) << 2;
    const int tid = threadIdx.x;
    const int k   = tid;

    __shared__ float y1c[4][512];   // [q][s*8+r] for chunk c

    const long y1base = (long)(b * LQ + q0) * 4096 + (c << 9);
    for (int t = tid; t < 512; t += 192) {   // 512 float4s = 4q x 512 floats
        const int qq = t >> 7, e = t & 127;
        const float4 v =
            *(const float4*)(y1p + y1base + (long)qq * 4096 + (e << 2));
        const int r  = e >> 4;
        const int s4 = (e & 15) << 2;
        y1c[qq][(s4 + 0) * 8 + r] = v.x;
        y1c[qq][(s4 + 1) * 8 + r] = v.y;
        y1c[qq][(s4 + 2) * 8 + r] = v.z;
        y1c[qq][(s4 + 3) * 8 + r] = v.w;
    }
    __syncthreads();
    if (k >= LK) return;

    const float* wb  = wbo + (c << 6);
    const float* ybc = y0t + (((long)(b * 8 + c) * 64) * 160 + k) * 8;

    float num[4], den[4];
#pragma unroll
    for (int q = 0; q < 4; q++) { num[q] = 0.f; den[q] = 0.f; }

    float4 a0 = *(const float4*)(ybc);
    float4 a1 = *(const float4*)(ybc + 4);
    for (int s = 0; s < 64; s++) {
        const float a[8] = {a0.x, a0.y, a0.z, a0.w, a1.x, a1.y, a1.z, a1.w};
        const int sn = (s + 1) & 63;          // last iter reloads s=0 (harmless)
        a0 = *(const float4*)(ybc + (long)sn * 1280);
        a1 = *(const float4*)(ybc + (long)sn * 1280 + 4);
        const float w = wb[s];
#pragma unroll
        for (int q = 0; q < 4; q++) {
            const float4 p0 = *(const float4*)(&y1c[q][s << 3]);
            const float4 p1 = *(const float4*)(&y1c[q][(s << 3) + 4]);
            float z = a[0] * p0.x;
            z = fmaf(a[1], p0.y, z); z = fmaf(a[2], p0.z, z); z = fmaf(a[3], p0.w, z);
            z = fmaf(a[4], p1.x, z); z = fmaf(a[5], p1.y, z);
            z = fmaf(a[6], p1.z, z); z = fmaf(a[7], p1.w, z);
            const float az = fabsf(z);
            num[q] = fmaf(copysignf(__builtin_amdgcn_sqrtf(az), z), w, num[q]);
            den[q] += az;
        }
    }
#pragma unroll
    for (int q = 0; q < 4; q++)
        scores_p[(((long)(b * LQ + q0 + q)) * 8 + c) * 160 + k] =
            num[q] / fmaxf(__builtin_amdgcn_sqrtf(den[q]), 1e-12f);
}

// ---------------------------------------------------------------------------
// Sum partials over c, softmax over k, att@vv, write attedT [B][512][LQ]
// (= row-major input of the final linear after the torch transpose/view).
// b_bo dropped: softmax is shift-invariant.
// ---------------------------------------------------------------------------
__global__ __launch_bounds__(256) void softmax_attv(
    const float* __restrict__ scores_p, const float* __restrict__ vv,
    float* __restrict__ attedT)
{
    const int b  = blockIdx.y;
    const int q0 = blockIdx.x << 2;
    const int tid = threadIdx.x;

    __shared__ float scs[4][160];
    __shared__ float invd[4];

    for (int t = tid; t < 640; t += 256) {
        const int q = t / 160;
        const int k = t - q * 160;
        const float* sp = scores_p + ((long)(b * LQ + q0 + q)) * 1280 + k;
        float s = 0.f;
#pragma unroll
        for (int c = 0; c < 8; c++) s += sp[c * 160];
        scs[q][k] = s;
    }
    __syncthreads();

    const int w    = tid >> 6;
    const int lane = tid & 63;
    {
        const int q = w;
        float m = -1e30f;
        for (int kk = lane; kk < LK; kk += 64) m = fmaxf(m, scs[q][kk]);
#pragma unroll
        for (int off = 32; off; off >>= 1) m = fmaxf(m, __shfl_xor(m, off, 64));
        float sum = 0.f;
        for (int kk = lane; kk < LK; kk += 64) {
            const float e = __expf(scs[q][kk] - m);
            scs[q][kk] = e;
            sum += e;
        }
#pragma unroll
        for (int off = 32; off; off >>= 1) sum += __shfl_xor(sum, off, 64);
        if (lane == 0) invd[q] = 1.f / sum;
    }
    __syncthreads();

    float acc[2][4] = {{0.f,0.f,0.f,0.f},{0.f,0.f,0.f,0.f}};
    const float* vb = vv + (long)b * (LK * 512);
    for (int kk = 0; kk < LK; kk++) {
        const float* vr = vb + kk * 512;
        const float p0 = scs[0][kk], p1 = scs[1][kk];
        const float p2 = scs[2][kk], p3 = scs[3][kk];
        const float v0 = vr[tid], v1 = vr[tid + 256];
        acc[0][0] = fmaf(p0, v0, acc[0][0]); acc[0][1] = fmaf(p1, v0, acc[0][1]);
        acc[0][2] = fmaf(p2, v0, acc[0][2]); acc[0][3] = fmaf(p3, v0, acc[0][3]);
        acc[1][0] = fmaf(p0, v1, acc[1][0]); acc[1][1] = fmaf(p1, v1, acc[1][1]);
        acc[1][2] = fmaf(p2, v1, acc[1][2]); acc[1][3] = fmaf(p3, v1, acc[1][3]);
    }
#pragma unroll
    for (int j = 0; j < 2; j++) {
        const int h = tid + (j << 8);
#pragma unroll
        for (int q = 0; q < 4; q++)
            attedT[((long)b * 512 + h) * 160 + q0 + q] = acc[j][q] * invd[q];
    }
}

// ---------------------------------------------------------------------------
extern "C" void kernel_launch(void* const* d_in, const int* in_sizes, int n_in,
                              void* d_out, int out_size, void* d_ws, size_t ws_size,
                              hipStream_t stream) {
    const float* v    = (const float*)d_in[0];
    const float* kin  = (const float*)d_in[1];
    const float* q    = (const float*)d_in[2];
    const float* w_v  = (const float*)d_in[3];
    const float* b_v  = (const float*)d_in[4];
    const float* w_k  = (const float*)d_in[5];
    const float* b_k  = (const float*)d_in[6];
    const float* w_q  = (const float*)d_in[7];
    const float* b_q  = (const float*)d_in[8];
    const float* w0   = (const float*)d_in[9];
    const float* b0   = (const float*)d_in[10];
    const float* w1   = (const float*)d_in[11];
    const float* b1   = (const float*)d_in[12];
    const float* wm0  = (const float*)d_in[13];
    const float* bm0  = (const float*)d_in[14];
    const float* wm1  = (const float*)d_in[15];
    const float* bm1  = (const float*)d_in[16];
    const float* w_bo = (const float*)d_in[17];
    (void)d_in[18];  // b_bo unused: softmax is shift-invariant
    const float* w_m  = (const float*)d_in[19];
    const float* b_m  = (const float*)d_in[20];

    float* ws       = (float*)d_ws;
    float* vv       = ws;                  // 655360
    float* kk       = ws + 655360;         // 655360
    float* qq       = ws + 1310720;        // 655360
    float* x0       = ws + 1966080;        // 655360
    float* x1       = ws + 2621440;        // 655360
    float* y1p      = ws + 3276800;        // 5242880  [B][LQ][c][r][s]
    float* y0t      = ws + 8519680;        // 5242880  [B][c][s][k][r]
    float* attedT   = ws + 13762560;       // 655360   [B][512][LQ]
    float* scores_p = ws + 655360;         // 1638400, aliases kk/qq/x0 (dead by then)

    GOps oA;
    oA.A[0] = v;   oA.W[0] = w_v; oA.Bi[0] = b_v; oA.C[0] = vv;
    oA.A[1] = kin; oA.W[1] = w_k; oA.Bi[1] = b_k; oA.C[1] = kk;
    oA.A[2] = q;   oA.W[2] = w_q; oA.Bi[2] = b_q; oA.C[2] = qq;
    hipLaunchKernelGGL(gemm_f, dim3(8, 20, 3), dim3(256), 0, stream, oA, 512);

    GOps oB;
    oB.A[0] = kk; oB.W[0] = w0; oB.Bi[0] = b0; oB.C[0] = x0;
    oB.A[1] = qq; oB.W[1] = w1; oB.Bi[1] = b1; oB.C[1] = x1;
    oB.A[2] = nullptr; oB.W[2] = nullptr; oB.Bi[2] = nullptr; oB.C[2] = nullptr;
    hipLaunchKernelGGL(gemm_f, dim3(8, 20, 2), dim3(256), 0, stream, oB, 512);

    hipLaunchKernelGGL(y_proj, dim3(8, 20, 16), dim3(256), 0, stream,
                       x0, wm0, bm0, x1, wm1, bm1, y0t, y1p);

    hipLaunchKernelGGL(score_partial, dim3(2560), dim3(192), 0, stream,
                       y1p, y0t, w_bo, scores_p);

    hipLaunchKernelGGL(softmax_attv, dim3(40, 8), dim3(256), 0, stream,
                       scores_p, vv, attedT);

    GOps oF;
    oF.A[0] = attedT; oF.W[0] = w_m; oF.Bi[0] = b_m; oF.C[0] = (float*)d_out;
    oF.A[1] = nullptr; oF.W[1] = nullptr; oF.Bi[1] = nullptr; oF.C[1] = nullptr;
    oF.A[2] = nullptr; oF.W[2] = nullptr; oF.Bi[2] = nullptr; oF.C[2] = nullptr;
    hipLaunchKernelGGL(gemm_f, dim3(8, 20, 1), dim3(256), 0, stream, oF, 512);
}